// Round 1
// baseline (32.900 us; speedup 1.0000x reference)
//
#include <hip/hip_runtime.h>

#define ALPHA    0.25f
#define EPS_LOSS 1e-8f

constexpr int BLOCKS  = 1024;
constexpr int THREADS = 256;
constexpr int WAVES   = THREADS / 64;

// One CORAL focal term. ce = tm*log(p+eps) + (1-tm)*log(1-p+eps) == log(pt+eps)
// where pt = tm ? p : 1-p. focal = (1-pt)^2, alpha_t = tm ? 0.25 : 0.75.
__device__ __forceinline__ float coral_term(float x, int tm) {
    float p  = 1.0f / (1.0f + __expf(-x));
    float pt = tm ? p : 1.0f - p;
    float om = 1.0f - pt;
    float at = tm ? ALPHA : 1.0f - ALPHA;
    float ce = __logf(pt + EPS_LOSS);
    return -at * om * om * ce;
}

__global__ __launch_bounds__(THREADS) void coral_main(
        const float* __restrict__ kl_logits,
        const float* __restrict__ jsnm_logits,
        const float* __restrict__ jsnl_logits,
        const float* __restrict__ cw,
        const int*   __restrict__ kl_t,
        const int*   __restrict__ jsnm_t,
        const int*   __restrict__ jsnl_t,
        float*       __restrict__ partials,
        int n) {
    // class weights are tiny + uniform-address: keep in registers
    const float w0 = cw[0], w1 = cw[1], w2 = cw[2], w3 = cw[3], w4 = cw[4];

    float s0 = 0.0f, s1 = 0.0f, s2 = 0.0f;

    for (int i = blockIdx.x * THREADS + threadIdx.x; i < n;
         i += gridDim.x * THREADS) {
        const int kt = kl_t[i];
        // select class weight with cndmask chain (kt in 0..4)
        float w = (kt == 0) ? w0 : (kt == 1) ? w1 : (kt == 2) ? w2
                : (kt == 3) ? w3 : w4;

        // --- kl loss: 4 logits, targets 0..4 ---
        const float4 kx = reinterpret_cast<const float4*>(kl_logits)[i];
        float a = coral_term(kx.x, 0 < kt) + coral_term(kx.y, 1 < kt)
                + coral_term(kx.z, 2 < kt) + coral_term(kx.w, 3 < kt);
        s0 += w * a;

        // --- jsnm loss: 3 logits, targets 0..3 ---
        const int mt = jsnm_t[i];
        const float* mrow = jsnm_logits + 3 * i;
        float b = coral_term(mrow[0], 0 < mt) + coral_term(mrow[1], 1 < mt)
                + coral_term(mrow[2], 2 < mt);
        s1 += w * b;

        // --- jsnl loss: 3 logits, targets 0..3 ---
        const int lt = jsnl_t[i];
        const float* lrow = jsnl_logits + 3 * i;
        float c = coral_term(lrow[0], 0 < lt) + coral_term(lrow[1], 1 < lt)
                + coral_term(lrow[2], 2 < lt);
        s2 += w * c;
    }

    // wave reduction (64 lanes)
    #pragma unroll
    for (int off = 32; off > 0; off >>= 1) {
        s0 += __shfl_xor(s0, off);
        s1 += __shfl_xor(s1, off);
        s2 += __shfl_xor(s2, off);
    }

    __shared__ float red[3][WAVES];
    const int lane = threadIdx.x & 63;
    const int wid  = threadIdx.x >> 6;
    if (lane == 0) {
        red[0][wid] = s0;
        red[1][wid] = s1;
        red[2][wid] = s2;
    }
    __syncthreads();
    if (threadIdx.x == 0) {
        float t0 = 0.0f, t1 = 0.0f, t2 = 0.0f;
        #pragma unroll
        for (int wv = 0; wv < WAVES; ++wv) {
            t0 += red[0][wv];
            t1 += red[1][wv];
            t2 += red[2][wv];
        }
        partials[blockIdx.x * 3 + 0] = t0;
        partials[blockIdx.x * 3 + 1] = t1;
        partials[blockIdx.x * 3 + 2] = t2;
    }
}

__global__ __launch_bounds__(THREADS) void coral_finalize(
        const float* __restrict__ partials, float* __restrict__ out,
        int nblocks, float n) {
    float s0 = 0.0f, s1 = 0.0f, s2 = 0.0f;
    for (int i = threadIdx.x; i < nblocks; i += THREADS) {
        s0 += partials[3 * i + 0];
        s1 += partials[3 * i + 1];
        s2 += partials[3 * i + 2];
    }
    #pragma unroll
    for (int off = 32; off > 0; off >>= 1) {
        s0 += __shfl_xor(s0, off);
        s1 += __shfl_xor(s1, off);
        s2 += __shfl_xor(s2, off);
    }
    __shared__ float red[3][WAVES];
    const int lane = threadIdx.x & 63;
    const int wid  = threadIdx.x >> 6;
    if (lane == 0) {
        red[0][wid] = s0;
        red[1][wid] = s1;
        red[2][wid] = s2;
    }
    __syncthreads();
    if (threadIdx.x == 0) {
        float t0 = 0.0f, t1 = 0.0f, t2 = 0.0f;
        #pragma unroll
        for (int wv = 0; wv < WAVES; ++wv) {
            t0 += red[0][wv];
            t1 += red[1][wv];
            t2 += red[2][wv];
        }
        const float l_kl   = t0 / (n * 4.0f);
        const float l_jsnm = t1 / (n * 3.0f);
        const float l_jsnl = t2 / (n * 3.0f);
        out[0] = (l_kl + l_jsnm + l_jsnl) / 3.0f;
        out[1] = l_kl;
        out[2] = l_jsnm;
        out[3] = l_jsnl;
    }
}

extern "C" void kernel_launch(void* const* d_in, const int* in_sizes, int n_in,
                              void* d_out, int out_size, void* d_ws, size_t ws_size,
                              hipStream_t stream) {
    const float* kl_logits   = (const float*)d_in[0];
    const float* jsnm_logits = (const float*)d_in[1];
    const float* jsnl_logits = (const float*)d_in[2];
    const float* cw          = (const float*)d_in[3];
    const int*   kl_t        = (const int*)d_in[4];
    const int*   jsnm_t      = (const int*)d_in[5];
    const int*   jsnl_t      = (const int*)d_in[6];
    const int n = in_sizes[4];  // kl_t element count == N

    float* partials = (float*)d_ws;              // BLOCKS*3 floats
    float* out      = (float*)d_out;             // (total, l_kl, l_jsnm, l_jsnl)

    coral_main<<<BLOCKS, THREADS, 0, stream>>>(
        kl_logits, jsnm_logits, jsnl_logits, cw, kl_t, jsnm_t, jsnl_t,
        partials, n);
    coral_finalize<<<1, THREADS, 0, stream>>>(partials, out, BLOCKS, (float)n);
}